// Round 8
// baseline (74.102 us; speedup 1.0000x reference)
//
#include <hip/hip_runtime.h>

typedef __attribute__((ext_vector_type(8))) short short8;
typedef __attribute__((ext_vector_type(4))) float f32x4;
typedef __attribute__((ext_vector_type(2))) unsigned u32x2;

// fp32 -> bf16 round-to-nearest-even
__device__ __forceinline__ unsigned short f2bf(float f) {
  unsigned u = __builtin_bit_cast(unsigned, f);
  u += 0x7fffu + ((u >> 16) & 1u);
  return (unsigned short)(u >> 16);
}
__device__ __forceinline__ float bf2f(unsigned short u) {
  return __builtin_bit_cast(float, (unsigned)u << 16);
}

// ---------------------------------------------------------------------------
// wprep: W1..W4 fp32 -> bf16, MFMA B-fragment swizzle. 288 blocks x 256 thr.
// ---------------------------------------------------------------------------
__global__ __launch_bounds__(256) void wprep(
    const float* __restrict__ W1, const float* __restrict__ W2,
    const float* __restrict__ W3, const float* __restrict__ W4,
    unsigned short* __restrict__ W1f, unsigned short* __restrict__ W2f,
    unsigned short* __restrict__ W3f, unsigned short* __restrict__ W4f) {
  int idx = (blockIdx.x * 256 + threadIdx.x) * 4;  // 0..294908
  const float* src; unsigned short* dst; int kb; int rel;
  if (idx < 98304)        { src = W1; dst = W1f; kb = 12; rel = idx; }
  else if (idx < 163840)  { src = W2; dst = W2f; kb = 8;  rel = idx - 98304; }
  else if (idx < 229376)  { src = W3; dst = W3f; kb = 8;  rel = idx - 163840; }
  else                    { src = W4; dst = W4f; kb = 8;  rel = idx - 229376; }
  int kk = rel >> 8, n0 = rel & 255;
  f32x4 t = *(const f32x4*)(src + rel);
  #pragma unroll
  for (int j = 0; j < 4; ++j) {
    int n = n0 + j;
    int lane = (n & 15) | (((kk >> 3) & 3) << 4);
    int di = (((n >> 4) * kb + (kk >> 5)) * 64 + lane) * 8 + (kk & 7);
    dst[di] = f2bf(t[j]);
  }
}

// ---------------------------------------------------------------------------
// fusedU: one batch (64 rows) per block, 512 thr (8 waves, N-split 32 cols).
// Phases: stage user->LDS(+out0 fp32 copy) | BAR | {waves0-1: column stats}
// overlapped with {all: user+RIS MFMA chunks} | BAR | loo MFMA chunk |
// H->LDS | BAR | L2 MFMA | store.  3 barriers, 49.25 KB LDS -> 3 blocks/CU.
// ---------------------------------------------------------------------------
__global__ __launch_bounds__(512, 6) void fusedU(
    const float* __restrict__ user, const float* __restrict__ ris,
    const unsigned short* __restrict__ W1f, const unsigned short* __restrict__ W2f,
    const float* __restrict__ b1, const float* __restrict__ b2,
    float* __restrict__ out0, unsigned short* __restrict__ meanb) {
  __shared__ unsigned short U[64 * 128];    // 16 KiB bf16 user tile, XOR-swizzled
  __shared__ unsigned short Hb[64 * 256];   // 32 KiB H, XOR-swizzled
  __shared__ unsigned short m1s[128], m2s[128], ams[128], risl[128];

  const int tid = threadIdx.x;
  const int bx = blockIdx.x;                 // batch index
  const size_t ubase = (size_t)bx * 8192;    // 64*128

  // ---- stage: user tile -> out0 (exact fp32) + U (bf16, swizzled) ----
  #pragma unroll
  for (int it = 0; it < 4; ++it) {
    int e = it * 2048 + tid * 4;             // float idx in tile
    f32x4 t = *(const f32x4*)(user + ubase + e);
    int row = e >> 7, col = e & 127;
    *(f32x4*)(out0 + (size_t)(bx * 64 + row) * 384 + col) = t;
    unsigned p0 = (unsigned)f2bf(t[0]) | ((unsigned)f2bf(t[1]) << 16);
    unsigned p1 = (unsigned)f2bf(t[2]) | ((unsigned)f2bf(t[3]) << 16);
    int cc = col >> 3, sub = col & 7;        // sub in {0,4}
    u32x2 p = {p0, p1};
    *(u32x2*)(U + row * 128 + ((cc ^ (row & 7)) << 3) + sub) = p;
  }
  if (tid < 128) risl[tid] = f2bf(ris[bx * 128 + tid]);
  __syncthreads();

  const int lane = tid & 63, wn = tid >> 6;  // 8 waves, 32-col slices
  const int r = lane & 15;
  const int k8 = (lane >> 4) * 8;
  const int j4 = (lane >> 4) * 4;

  // ---- stats (waves 0-1 only): per-column mean/max1/max2/argmax ----
  if (tid < 128) {
    int c = tid;
    int cc = c >> 3, sub = c & 7;
    float m1 = -3.402823466e38f, m2 = -3.402823466e38f, s = 0.f;
    int amx = 0;
    #pragma unroll 8
    for (int row = 0; row < 64; ++row) {
      float v = bf2f(U[row * 128 + ((cc ^ (row & 7)) << 3) + sub]);
      s += v;
      if (v > m1) { m2 = m1; m1 = v; amx = row; }
      else if (v > m2) { m2 = v; }
    }
    m1s[c] = f2bf(m1); m2s[c] = f2bf(m2); ams[c] = (unsigned short)amx;
    meanb[bx * 128 + c] = f2bf(s * (1.f / 64.f));
  }

  // ---- layer 1, stats-independent chunks (all waves, overlaps stats) ----
  f32x4 acc[4][2];
  #pragma unroll
  for (int a = 0; a < 4; ++a) { acc[a][0] = (f32x4)0.f; acc[a][1] = (f32x4)0.f; }

  #pragma unroll
  for (int fs = 0; fs < 4; ++fs) {           // user chunk (LDS)
    short8 af[4];
    #pragma unroll
    for (int mf = 0; mf < 4; ++mf) {
      int row = mf * 16 + r;
      int cc = fs * 4 + (lane >> 4);
      af[mf] = *(const short8*)(U + row * 128 + ((cc ^ (row & 7)) << 3));
    }
    short8 w0 = *(const short8*)&W1f[(size_t)(((wn * 2 + 0) * 12 + fs) * 64 + lane) * 8];
    short8 w1 = *(const short8*)&W1f[(size_t)(((wn * 2 + 1) * 12 + fs) * 64 + lane) * 8];
    #pragma unroll
    for (int mf = 0; mf < 4; ++mf) {
      acc[mf][0] = __builtin_amdgcn_mfma_f32_16x16x32_bf16(af[mf], w0, acc[mf][0], 0, 0, 0);
      acc[mf][1] = __builtin_amdgcn_mfma_f32_16x16x32_bf16(af[mf], w1, acc[mf][1], 0, 0, 0);
    }
  }
  #pragma unroll
  for (int fs = 0; fs < 4; ++fs) {           // RIS broadcast chunk (LDS risl)
    short8 v = *(const short8*)(risl + fs * 32 + k8);
    short8 w0 = *(const short8*)&W1f[(size_t)(((wn * 2 + 0) * 12 + 8 + fs) * 64 + lane) * 8];
    short8 w1 = *(const short8*)&W1f[(size_t)(((wn * 2 + 1) * 12 + 8 + fs) * 64 + lane) * 8];
    #pragma unroll
    for (int mf = 0; mf < 4; ++mf) {
      acc[mf][0] = __builtin_amdgcn_mfma_f32_16x16x32_bf16(v, w0, acc[mf][0], 0, 0, 0);
      acc[mf][1] = __builtin_amdgcn_mfma_f32_16x16x32_bf16(v, w1, acc[mf][1], 0, 0, 0);
    }
  }
  __syncthreads();   // stats visible

  #pragma unroll
  for (int fs = 0; fs < 4; ++fs) {           // leave-one-out chunk (stats)
    int c0 = fs * 32 + k8;
    short8 m1v = *(const short8*)(m1s + c0);
    short8 m2v = *(const short8*)(m2s + c0);
    short8 amv = *(const short8*)(ams + c0);
    short8 w0 = *(const short8*)&W1f[(size_t)(((wn * 2 + 0) * 12 + 4 + fs) * 64 + lane) * 8];
    short8 w1 = *(const short8*)&W1f[(size_t)(((wn * 2 + 1) * 12 + 4 + fs) * 64 + lane) * 8];
    #pragma unroll
    for (int mf = 0; mf < 4; ++mf) {
      int rr = mf * 16 + r;
      short8 t;
      #pragma unroll
      for (int j = 0; j < 8; ++j)
        t[j] = ((unsigned short)amv[j] == (unsigned short)rr) ? m2v[j] : m1v[j];
      acc[mf][0] = __builtin_amdgcn_mfma_f32_16x16x32_bf16(t, w0, acc[mf][0], 0, 0, 0);
      acc[mf][1] = __builtin_amdgcn_mfma_f32_16x16x32_bf16(t, w1, acc[mf][1], 0, 0, 0);
    }
  }

  // ---- H: bias + relu -> LDS (swizzled) ----
  float ba[2] = { b1[wn * 32 + r], b1[wn * 32 + 16 + r] };
  #pragma unroll
  for (int mf = 0; mf < 4; ++mf)
    #pragma unroll
    for (int nf = 0; nf < 2; ++nf)
      #pragma unroll
      for (int j = 0; j < 4; ++j) {
        int rr = mf * 16 + j4 + j;
        int col = wn * 32 + nf * 16 + r;
        int cc = col >> 3;
        Hb[rr * 256 + ((cc ^ (rr & 7)) << 3) + (col & 7)] =
            f2bf(fmaxf(acc[mf][nf][j] + ba[nf], 0.f));
      }
  __syncthreads();

  // ---- layer 2: 64 MFMA/wave ----
  f32x4 acc2[4][2];
  #pragma unroll
  for (int a = 0; a < 4; ++a) { acc2[a][0] = (f32x4)0.f; acc2[a][1] = (f32x4)0.f; }
  #pragma unroll
  for (int kc = 0; kc < 8; ++kc) {
    short8 af[4];
    #pragma unroll
    for (int mf = 0; mf < 4; ++mf) {
      int rr = mf * 16 + r;
      int cc = kc * 4 + (lane >> 4);
      af[mf] = *(const short8*)(Hb + rr * 256 + ((cc ^ (rr & 7)) << 3));
    }
    short8 w0 = *(const short8*)&W2f[(size_t)(((wn * 2 + 0) * 8 + kc) * 64 + lane) * 8];
    short8 w1 = *(const short8*)&W2f[(size_t)(((wn * 2 + 1) * 8 + kc) * 64 + lane) * 8];
    #pragma unroll
    for (int mf = 0; mf < 4; ++mf) {
      acc2[mf][0] = __builtin_amdgcn_mfma_f32_16x16x32_bf16(af[mf], w0, acc2[mf][0], 0, 0, 0);
      acc2[mf][1] = __builtin_amdgcn_mfma_f32_16x16x32_bf16(af[mf], w1, acc2[mf][1], 0, 0, 0);
    }
  }

  // ---- store out0 cols 128..383 ----
  float bb[2] = { b2[wn * 32 + r], b2[wn * 32 + 16 + r] };
  #pragma unroll
  for (int mf = 0; mf < 4; ++mf)
    #pragma unroll
    for (int nf = 0; nf < 2; ++nf)
      #pragma unroll
      for (int j = 0; j < 4; ++j) {
        int rr = mf * 16 + j4 + j;
        int col = wn * 32 + nf * 16 + r;
        out0[(size_t)(bx * 64 + rr) * 384 + 128 + col] = acc2[mf][nf][j] + bb[nf];
      }
}

// ---------------------------------------------------------------------------
// fusedR: RIS path. 16 blocks x 512 thr, 64 batches per block.
// A = [ris (fp32->bf16 in-reg) | meanb]; also writes out1 cols 0..127 fp32.
// ---------------------------------------------------------------------------
__global__ __launch_bounds__(512, 4) void fusedR(
    const float* __restrict__ ris, const unsigned short* __restrict__ meanb,
    const unsigned short* __restrict__ W3f, const unsigned short* __restrict__ W4f,
    const float* __restrict__ b3, const float* __restrict__ b4,
    float* __restrict__ out1) {
  __shared__ unsigned short Hb[64 * 256];   // 32 KiB, XOR-swizzled

  const int tid = threadIdx.x;
  const int row0 = blockIdx.x * 64;

  // exact fp32 copy: out1 cols 0..127
  #pragma unroll
  for (int it = 0; it < 4; ++it) {
    int e = it * 2048 + tid * 4;
    f32x4 t = *(const f32x4*)(ris + (size_t)row0 * 128 + e);
    int row = e >> 7, col = e & 127;
    *(f32x4*)(out1 + (size_t)(row0 + row) * 384 + col) = t;
  }

  const int lane = tid & 63, wn = tid >> 6;
  const int r = lane & 15;
  const int k8 = (lane >> 4) * 8;
  const int j4 = (lane >> 4) * 4;

  f32x4 acc[4][2];
  #pragma unroll
  for (int a = 0; a < 4; ++a) { acc[a][0] = (f32x4)0.f; acc[a][1] = (f32x4)0.f; }

  #pragma unroll
  for (int fs = 0; fs < 8; ++fs) {
    short8 af[4];
    if (fs < 4) {
      #pragma unroll
      for (int mf = 0; mf < 4; ++mf) {
        const float* p = &ris[(size_t)(row0 + mf * 16 + r) * 128 + fs * 32 + k8];
        f32x4 t0 = *(const f32x4*)p;
        f32x4 t1 = *(const f32x4*)(p + 4);
        short8 t;
        #pragma unroll
        for (int j = 0; j < 4; ++j) { t[j] = (short)f2bf(t0[j]); t[4 + j] = (short)f2bf(t1[j]); }
        af[mf] = t;
      }
    } else {
      #pragma unroll
      for (int mf = 0; mf < 4; ++mf)
        af[mf] = *(const short8*)&meanb[(size_t)(row0 + mf * 16 + r) * 128 + (fs - 4) * 32 + k8];
    }
    short8 w0 = *(const short8*)&W3f[(size_t)(((wn * 2 + 0) * 8 + fs) * 64 + lane) * 8];
    short8 w1 = *(const short8*)&W3f[(size_t)(((wn * 2 + 1) * 8 + fs) * 64 + lane) * 8];
    #pragma unroll
    for (int mf = 0; mf < 4; ++mf) {
      acc[mf][0] = __builtin_amdgcn_mfma_f32_16x16x32_bf16(af[mf], w0, acc[mf][0], 0, 0, 0);
      acc[mf][1] = __builtin_amdgcn_mfma_f32_16x16x32_bf16(af[mf], w1, acc[mf][1], 0, 0, 0);
    }
  }

  float ba[2] = { b3[wn * 32 + r], b3[wn * 32 + 16 + r] };
  #pragma unroll
  for (int mf = 0; mf < 4; ++mf)
    #pragma unroll
    for (int nf = 0; nf < 2; ++nf)
      #pragma unroll
      for (int j = 0; j < 4; ++j) {
        int rr = mf * 16 + j4 + j;
        int col = wn * 32 + nf * 16 + r;
        int cc = col >> 3;
        Hb[rr * 256 + ((cc ^ (rr & 7)) << 3) + (col & 7)] =
            f2bf(fmaxf(acc[mf][nf][j] + ba[nf], 0.f));
      }
  __syncthreads();

  f32x4 acc2[4][2];
  #pragma unroll
  for (int a = 0; a < 4; ++a) { acc2[a][0] = (f32x4)0.f; acc2[a][1] = (f32x4)0.f; }
  #pragma unroll
  for (int kc = 0; kc < 8; ++kc) {
    short8 af[4];
    #pragma unroll
    for (int mf = 0; mf < 4; ++mf) {
      int rr = mf * 16 + r;
      int cc = kc * 4 + (lane >> 4);
      af[mf] = *(const short8*)(Hb + rr * 256 + ((cc ^ (rr & 7)) << 3));
    }
    short8 w0 = *(const short8*)&W4f[(size_t)(((wn * 2 + 0) * 8 + kc) * 64 + lane) * 8];
    short8 w1 = *(const short8*)&W4f[(size_t)(((wn * 2 + 1) * 8 + kc) * 64 + lane) * 8];
    #pragma unroll
    for (int mf = 0; mf < 4; ++mf) {
      acc2[mf][0] = __builtin_amdgcn_mfma_f32_16x16x32_bf16(af[mf], w0, acc2[mf][0], 0, 0, 0);
      acc2[mf][1] = __builtin_amdgcn_mfma_f32_16x16x32_bf16(af[mf], w1, acc2[mf][1], 0, 0, 0);
    }
  }

  float bb[2] = { b4[wn * 32 + r], b4[wn * 32 + 16 + r] };
  #pragma unroll
  for (int mf = 0; mf < 4; ++mf)
    #pragma unroll
    for (int nf = 0; nf < 2; ++nf)
      #pragma unroll
      for (int j = 0; j < 4; ++j) {
        int rr = mf * 16 + j4 + j;
        int col = wn * 32 + nf * 16 + r;
        out1[(size_t)(row0 + rr) * 384 + 128 + col] = acc2[mf][nf][j] + bb[nf];
      }
}

// ---------------------------------------------------------------------------
extern "C" void kernel_launch(void* const* d_in, const int* in_sizes, int n_in,
                              void* d_out, int out_size, void* d_ws, size_t ws_size,
                              hipStream_t stream) {
  const float* user = (const float*)d_in[0];
  const float* ris  = (const float*)d_in[1];
  const float* W1 = (const float*)d_in[4];
  const float* b1 = (const float*)d_in[5];
  const float* W2 = (const float*)d_in[6];
  const float* b2 = (const float*)d_in[7];
  const float* W3 = (const float*)d_in[8];
  const float* b3 = (const float*)d_in[9];
  const float* W4 = (const float*)d_in[10];
  const float* b4 = (const float*)d_in[11];

  float* out0 = (float*)d_out;                         // (65536, 384)
  float* out1 = out0 + (size_t)65536 * 384;            // (1024, 384)

  char* ws = (char*)d_ws;
  unsigned short* meanb = (unsigned short*)(ws);            // 131072 bf16, 256 KiB
  unsigned short* W1f   = (unsigned short*)(ws + 262144);   // 98304 bf16, 192 KiB
  unsigned short* W2f   = (unsigned short*)(ws + 458752);   // 65536 bf16, 128 KiB
  unsigned short* W3f   = (unsigned short*)(ws + 589824);   // 65536 bf16, 128 KiB
  unsigned short* W4f   = (unsigned short*)(ws + 720896);   // 65536 bf16, 128 KiB

  hipLaunchKernelGGL(wprep, dim3(288), dim3(256), 0, stream,
                     W1, W2, W3, W4, W1f, W2f, W3f, W4f);
  hipLaunchKernelGGL(fusedU, dim3(1024), dim3(512), 0, stream,
                     user, ris, W1f, W2f, b1, b2, out0, meanb);
  hipLaunchKernelGGL(fusedR, dim3(16), dim3(512), 0, stream,
                     ris, meanb, W3f, W4f, b3, b4, out1);
}

// Round 10
// 70.497 us; speedup vs baseline: 1.0511x; 1.0511x over previous
//
#include <hip/hip_runtime.h>

typedef __attribute__((ext_vector_type(8))) short short8;
typedef __attribute__((ext_vector_type(4))) float f32x4;
typedef __attribute__((ext_vector_type(2))) unsigned u32x2;

// fp32 -> bf16 round-to-nearest-even (single)
__device__ __forceinline__ unsigned short f2bf(float f) {
  unsigned u = __builtin_bit_cast(unsigned, f);
  u += 0x7fffu + ((u >> 16) & 1u);
  return (unsigned short)(u >> 16);
}
__device__ __forceinline__ float bf2f(unsigned short u) {
  return __builtin_bit_cast(float, (unsigned)u << 16);
}
// fp32 pair -> packed bf16x2 via v_cvt_pk_bf16_f32 (no builtin on gfx950)
__device__ __forceinline__ unsigned pkbf(float a, float b) {
  unsigned r;
  asm("v_cvt_pk_bf16_f32 %0, %1, %2" : "=v"(r) : "v"(a), "v"(b));
  return r;
}

// ---------------------------------------------------------------------------
// wprep: W1..W4 fp32 -> bf16, MFMA B-fragment swizzle. 288 blocks x 256 thr.
// ---------------------------------------------------------------------------
__global__ __launch_bounds__(256) void wprep(
    const float* __restrict__ W1, const float* __restrict__ W2,
    const float* __restrict__ W3, const float* __restrict__ W4,
    unsigned short* __restrict__ W1f, unsigned short* __restrict__ W2f,
    unsigned short* __restrict__ W3f, unsigned short* __restrict__ W4f) {
  int idx = (blockIdx.x * 256 + threadIdx.x) * 4;  // 0..294908
  const float* src; unsigned short* dst; int kb; int rel;
  if (idx < 98304)        { src = W1; dst = W1f; kb = 12; rel = idx; }
  else if (idx < 163840)  { src = W2; dst = W2f; kb = 8;  rel = idx - 98304; }
  else if (idx < 229376)  { src = W3; dst = W3f; kb = 8;  rel = idx - 163840; }
  else                    { src = W4; dst = W4f; kb = 8;  rel = idx - 229376; }
  int kk = rel >> 8, n0 = rel & 255;
  f32x4 t = *(const f32x4*)(src + rel);
  #pragma unroll
  for (int j = 0; j < 4; ++j) {
    int n = n0 + j;
    int lane = (n & 15) | (((kk >> 3) & 3) << 4);
    int di = (((n >> 4) * kb + (kk >> 5)) * 64 + lane) * 8 + (kk & 7);
    dst[di] = f2bf(t[j]);
  }
}

// ---------------------------------------------------------------------------
// fusedU: one batch (64 rows) per block, 512 thr (8 waves, N-split 32 cols).
// LDS 50176 B -> 3 blocks/CU (needs VGPR <= 85; launch_bounds(512,4) leaves
// the allocator free -- round-8's (512,6) forced spills, 147 MB scratch).
// Phases: stage user->LDS(+out0 fp32 copy) | BAR | {waves0-1: column stats}
// overlapped with {all: user+RIS MFMA chunks} | BAR | loo MFMA | H->LDS |
// BAR | L2 MFMA | store.
// ---------------------------------------------------------------------------
__global__ __launch_bounds__(512, 4) void fusedU(
    const float* __restrict__ user, const float* __restrict__ ris,
    const unsigned short* __restrict__ W1f, const unsigned short* __restrict__ W2f,
    const float* __restrict__ b1, const float* __restrict__ b2,
    float* __restrict__ out0, unsigned short* __restrict__ meanb) {
  __shared__ unsigned short U[64 * 128];    // 16 KiB bf16 user tile, XOR-swizzled
  __shared__ unsigned short Hb[64 * 256];   // 32 KiB H, XOR-swizzled
  __shared__ unsigned short m1s[128], m2s[128], ams[128], risl[128];

  const int tid = threadIdx.x;
  const int bx = blockIdx.x;                 // batch index
  const size_t ubase = (size_t)bx * 8192;    // 64*128

  // ---- stage: user tile -> out0 (exact fp32) + U (bf16, swizzled) ----
  #pragma unroll
  for (int it = 0; it < 4; ++it) {
    int e = it * 2048 + tid * 4;             // float idx in tile
    f32x4 t = *(const f32x4*)(user + ubase + e);
    int row = e >> 7, col = e & 127;
    *(f32x4*)(out0 + (size_t)(bx * 64 + row) * 384 + col) = t;
    u32x2 p = { pkbf(t[0], t[1]), pkbf(t[2], t[3]) };
    int cc = col >> 3, sub = col & 7;        // sub in {0,4}
    *(u32x2*)(U + row * 128 + ((cc ^ (row & 7)) << 3) + sub) = p;
  }
  if (tid < 128) risl[tid] = f2bf(ris[bx * 128 + tid]);
  __syncthreads();

  const int lane = tid & 63, wn = tid >> 6;  // 8 waves, 32-col slices
  const int r = lane & 15;
  const int k8 = (lane >> 4) * 8;
  const int j4 = (lane >> 4) * 4;

  // ---- stats (waves 0-1 only): per-column mean/max1/max2/argmax ----
  if (tid < 128) {
    int c = tid;
    int cc = c >> 3, sub = c & 7;
    float m1 = -3.402823466e38f, m2 = -3.402823466e38f, s = 0.f;
    int amx = 0;
    #pragma unroll 8
    for (int row = 0; row < 64; ++row) {
      float v = bf2f(U[row * 128 + ((cc ^ (row & 7)) << 3) + sub]);
      s += v;
      if (v > m1) { m2 = m1; m1 = v; amx = row; }
      else if (v > m2) { m2 = v; }
    }
    m1s[c] = f2bf(m1); m2s[c] = f2bf(m2); ams[c] = (unsigned short)amx;
    meanb[bx * 128 + c] = f2bf(s * (1.f / 64.f));
  }

  // ---- layer 1, stats-independent chunks (all waves, overlaps stats) ----
  f32x4 acc[4][2];
  #pragma unroll
  for (int a = 0; a < 4; ++a) { acc[a][0] = (f32x4)0.f; acc[a][1] = (f32x4)0.f; }

  #pragma unroll
  for (int fs = 0; fs < 4; ++fs) {           // user chunk (LDS)
    short8 af[4];
    #pragma unroll
    for (int mf = 0; mf < 4; ++mf) {
      int row = mf * 16 + r;
      int cc = fs * 4 + (lane >> 4);
      af[mf] = *(const short8*)(U + row * 128 + ((cc ^ (row & 7)) << 3));
    }
    short8 w0 = *(const short8*)&W1f[(size_t)(((wn * 2 + 0) * 12 + fs) * 64 + lane) * 8];
    short8 w1 = *(const short8*)&W1f[(size_t)(((wn * 2 + 1) * 12 + fs) * 64 + lane) * 8];
    #pragma unroll
    for (int mf = 0; mf < 4; ++mf) {
      acc[mf][0] = __builtin_amdgcn_mfma_f32_16x16x32_bf16(af[mf], w0, acc[mf][0], 0, 0, 0);
      acc[mf][1] = __builtin_amdgcn_mfma_f32_16x16x32_bf16(af[mf], w1, acc[mf][1], 0, 0, 0);
    }
  }
  #pragma unroll
  for (int fs = 0; fs < 4; ++fs) {           // RIS broadcast chunk (LDS risl)
    short8 v = *(const short8*)(risl + fs * 32 + k8);
    short8 w0 = *(const short8*)&W1f[(size_t)(((wn * 2 + 0) * 12 + 8 + fs) * 64 + lane) * 8];
    short8 w1 = *(const short8*)&W1f[(size_t)(((wn * 2 + 1) * 12 + 8 + fs) * 64 + lane) * 8];
    #pragma unroll
    for (int mf = 0; mf < 4; ++mf) {
      acc[mf][0] = __builtin_amdgcn_mfma_f32_16x16x32_bf16(v, w0, acc[mf][0], 0, 0, 0);
      acc[mf][1] = __builtin_amdgcn_mfma_f32_16x16x32_bf16(v, w1, acc[mf][1], 0, 0, 0);
    }
  }
  __syncthreads();   // stats visible

  #pragma unroll
  for (int fs = 0; fs < 4; ++fs) {           // leave-one-out chunk (stats)
    int c0 = fs * 32 + k8;
    short8 m1v = *(const short8*)(m1s + c0);
    short8 m2v = *(const short8*)(m2s + c0);
    short8 amv = *(const short8*)(ams + c0);
    short8 w0 = *(const short8*)&W1f[(size_t)(((wn * 2 + 0) * 12 + 4 + fs) * 64 + lane) * 8];
    short8 w1 = *(const short8*)&W1f[(size_t)(((wn * 2 + 1) * 12 + 4 + fs) * 64 + lane) * 8];
    #pragma unroll
    for (int mf = 0; mf < 4; ++mf) {
      int rr = mf * 16 + r;
      short8 t;
      #pragma unroll
      for (int j = 0; j < 8; ++j)
        t[j] = ((unsigned short)amv[j] == (unsigned short)rr) ? m2v[j] : m1v[j];
      acc[mf][0] = __builtin_amdgcn_mfma_f32_16x16x32_bf16(t, w0, acc[mf][0], 0, 0, 0);
      acc[mf][1] = __builtin_amdgcn_mfma_f32_16x16x32_bf16(t, w1, acc[mf][1], 0, 0, 0);
    }
  }

  // ---- H: bias + relu -> LDS (swizzled) ----
  float ba[2] = { b1[wn * 32 + r], b1[wn * 32 + 16 + r] };
  #pragma unroll
  for (int mf = 0; mf < 4; ++mf)
    #pragma unroll
    for (int nf = 0; nf < 2; ++nf)
      #pragma unroll
      for (int j = 0; j < 4; ++j) {
        int rr = mf * 16 + j4 + j;
        int col = wn * 32 + nf * 16 + r;
        int cc = col >> 3;
        Hb[rr * 256 + ((cc ^ (rr & 7)) << 3) + (col & 7)] =
            f2bf(fmaxf(acc[mf][nf][j] + ba[nf], 0.f));
      }
  __syncthreads();

  // ---- layer 2: 64 MFMA/wave ----
  f32x4 acc2[4][2];
  #pragma unroll
  for (int a = 0; a < 4; ++a) { acc2[a][0] = (f32x4)0.f; acc2[a][1] = (f32x4)0.f; }
  #pragma unroll
  for (int kc = 0; kc < 8; ++kc) {
    short8 af[4];
    #pragma unroll
    for (int mf = 0; mf < 4; ++mf) {
      int rr = mf * 16 + r;
      int cc = kc * 4 + (lane >> 4);
      af[mf] = *(const short8*)(Hb + rr * 256 + ((cc ^ (rr & 7)) << 3));
    }
    short8 w0 = *(const short8*)&W2f[(size_t)(((wn * 2 + 0) * 8 + kc) * 64 + lane) * 8];
    short8 w1 = *(const short8*)&W2f[(size_t)(((wn * 2 + 1) * 8 + kc) * 64 + lane) * 8];
    #pragma unroll
    for (int mf = 0; mf < 4; ++mf) {
      acc2[mf][0] = __builtin_amdgcn_mfma_f32_16x16x32_bf16(af[mf], w0, acc2[mf][0], 0, 0, 0);
      acc2[mf][1] = __builtin_amdgcn_mfma_f32_16x16x32_bf16(af[mf], w1, acc2[mf][1], 0, 0, 0);
    }
  }

  // ---- store out0 cols 128..383 ----
  float bb[2] = { b2[wn * 32 + r], b2[wn * 32 + 16 + r] };
  #pragma unroll
  for (int mf = 0; mf < 4; ++mf)
    #pragma unroll
    for (int nf = 0; nf < 2; ++nf)
      #pragma unroll
      for (int j = 0; j < 4; ++j) {
        int rr = mf * 16 + j4 + j;
        int col = wn * 32 + nf * 16 + r;
        out0[(size_t)(bx * 64 + rr) * 384 + 128 + col] = acc2[mf][nf][j] + bb[nf];
      }
}

// ---------------------------------------------------------------------------
// fusedR: RIS path. 16 blocks x 512 thr, 64 batches per block.
// A = [ris (fp32->bf16 in-reg) | meanb]; also writes out1 cols 0..127 fp32.
// ---------------------------------------------------------------------------
__global__ __launch_bounds__(512, 4) void fusedR(
    const float* __restrict__ ris, const unsigned short* __restrict__ meanb,
    const unsigned short* __restrict__ W3f, const unsigned short* __restrict__ W4f,
    const float* __restrict__ b3, const float* __restrict__ b4,
    float* __restrict__ out1) {
  __shared__ unsigned short Hb[64 * 256];   // 32 KiB, XOR-swizzled

  const int tid = threadIdx.x;
  const int row0 = blockIdx.x * 64;

  // exact fp32 copy: out1 cols 0..127
  #pragma unroll
  for (int it = 0; it < 4; ++it) {
    int e = it * 2048 + tid * 4;
    f32x4 t = *(const f32x4*)(ris + (size_t)row0 * 128 + e);
    int row = e >> 7, col = e & 127;
    *(f32x4*)(out1 + (size_t)(row0 + row) * 384 + col) = t;
  }

  const int lane = tid & 63, wn = tid >> 6;
  const int r = lane & 15;
  const int k8 = (lane >> 4) * 8;
  const int j4 = (lane >> 4) * 4;

  f32x4 acc[4][2];
  #pragma unroll
  for (int a = 0; a < 4; ++a) { acc[a][0] = (f32x4)0.f; acc[a][1] = (f32x4)0.f; }

  #pragma unroll
  for (int fs = 0; fs < 8; ++fs) {
    short8 af[4];
    if (fs < 4) {
      #pragma unroll
      for (int mf = 0; mf < 4; ++mf) {
        const float* p = &ris[(size_t)(row0 + mf * 16 + r) * 128 + fs * 32 + k8];
        f32x4 t0 = *(const f32x4*)p;
        f32x4 t1 = *(const f32x4*)(p + 4);
        short8 t;
        #pragma unroll
        for (int j = 0; j < 4; ++j) { t[j] = (short)f2bf(t0[j]); t[4 + j] = (short)f2bf(t1[j]); }
        af[mf] = t;
      }
    } else {
      #pragma unroll
      for (int mf = 0; mf < 4; ++mf)
        af[mf] = *(const short8*)&meanb[(size_t)(row0 + mf * 16 + r) * 128 + (fs - 4) * 32 + k8];
    }
    short8 w0 = *(const short8*)&W3f[(size_t)(((wn * 2 + 0) * 8 + fs) * 64 + lane) * 8];
    short8 w1 = *(const short8*)&W3f[(size_t)(((wn * 2 + 1) * 8 + fs) * 64 + lane) * 8];
    #pragma unroll
    for (int mf = 0; mf < 4; ++mf) {
      acc[mf][0] = __builtin_amdgcn_mfma_f32_16x16x32_bf16(af[mf], w0, acc[mf][0], 0, 0, 0);
      acc[mf][1] = __builtin_amdgcn_mfma_f32_16x16x32_bf16(af[mf], w1, acc[mf][1], 0, 0, 0);
    }
  }

  float ba[2] = { b3[wn * 32 + r], b3[wn * 32 + 16 + r] };
  #pragma unroll
  for (int mf = 0; mf < 4; ++mf)
    #pragma unroll
    for (int nf = 0; nf < 2; ++nf)
      #pragma unroll
      for (int j = 0; j < 4; ++j) {
        int rr = mf * 16 + j4 + j;
        int col = wn * 32 + nf * 16 + r;
        int cc = col >> 3;
        Hb[rr * 256 + ((cc ^ (rr & 7)) << 3) + (col & 7)] =
            f2bf(fmaxf(acc[mf][nf][j] + ba[nf], 0.f));
      }
  __syncthreads();

  f32x4 acc2[4][2];
  #pragma unroll
  for (int a = 0; a < 4; ++a) { acc2[a][0] = (f32x4)0.f; acc2[a][1] = (f32x4)0.f; }
  #pragma unroll
  for (int kc = 0; kc < 8; ++kc) {
    short8 af[4];
    #pragma unroll
    for (int mf = 0; mf < 4; ++mf) {
      int rr = mf * 16 + r;
      int cc = kc * 4 + (lane >> 4);
      af[mf] = *(const short8*)(Hb + rr * 256 + ((cc ^ (rr & 7)) << 3));
    }
    short8 w0 = *(const short8*)&W4f[(size_t)(((wn * 2 + 0) * 8 + kc) * 64 + lane) * 8];
    short8 w1 = *(const short8*)&W4f[(size_t)(((wn * 2 + 1) * 8 + kc) * 64 + lane) * 8];
    #pragma unroll
    for (int mf = 0; mf < 4; ++mf) {
      acc2[mf][0] = __builtin_amdgcn_mfma_f32_16x16x32_bf16(af[mf], w0, acc2[mf][0], 0, 0, 0);
      acc2[mf][1] = __builtin_amdgcn_mfma_f32_16x16x32_bf16(af[mf], w1, acc2[mf][1], 0, 0, 0);
    }
  }

  float bb[2] = { b4[wn * 32 + r], b4[wn * 32 + 16 + r] };
  #pragma unroll
  for (int mf = 0; mf < 4; ++mf)
    #pragma unroll
    for (int nf = 0; nf < 2; ++nf)
      #pragma unroll
      for (int j = 0; j < 4; ++j) {
        int rr = mf * 16 + j4 + j;
        int col = wn * 32 + nf * 16 + r;
        out1[(size_t)(row0 + rr) * 384 + 128 + col] = acc2[mf][nf][j] + bb[nf];
      }
}

// ---------------------------------------------------------------------------
extern "C" void kernel_launch(void* const* d_in, const int* in_sizes, int n_in,
                              void* d_out, int out_size, void* d_ws, size_t ws_size,
                              hipStream_t stream) {
  const float* user = (const float*)d_in[0];
  const float* ris  = (const float*)d_in[1];
  const float* W1 = (const float*)d_in[4];
  const float* b1 = (const float*)d_in[5];
  const float* W2 = (const float*)d_in[6];
  const float* b2 = (const float*)d_in[7];
  const float* W3 = (const float*)d_in[8];
  const float* b3 = (const float*)d_in[9];
  const float* W4 = (const float*)d_in[10];
  const float* b4 = (const float*)d_in[11];

  float* out0 = (float*)d_out;                         // (65536, 384)
  float* out1 = out0 + (size_t)65536 * 384;            // (1024, 384)

  char* ws = (char*)d_ws;
  unsigned short* meanb = (unsigned short*)(ws);            // 131072 bf16, 256 KiB
  unsigned short* W1f   = (unsigned short*)(ws + 262144);   // 98304 bf16, 192 KiB
  unsigned short* W2f   = (unsigned short*)(ws + 458752);   // 65536 bf16, 128 KiB
  unsigned short* W3f   = (unsigned short*)(ws + 589824);   // 65536 bf16, 128 KiB
  unsigned short* W4f   = (unsigned short*)(ws + 720896);   // 65536 bf16, 128 KiB

  hipLaunchKernelGGL(wprep, dim3(288), dim3(256), 0, stream,
                     W1, W2, W3, W4, W1f, W2f, W3f, W4f);
  hipLaunchKernelGGL(fusedU, dim3(1024), dim3(512), 0, stream,
                     user, ris, W1f, W2f, b1, b2, out0, meanb);
  hipLaunchKernelGGL(fusedR, dim3(16), dim3(512), 0, stream,
                     ris, meanb, W3f, W4f, b3, b4, out1);
}